// Round 13
// baseline (5593.475 us; speedup 1.0000x reference)
//
#include <hip/hip_runtime.h>
#include <stdint.h>

#define B_ 256
#define S_ 512
#define H_ 256
#define G_ 1024
#define CHUNK 32
#define NCHUNK (S_ / CHUNK)

typedef __attribute__((ext_vector_type(8))) short bf16x8;
typedef __attribute__((ext_vector_type(4))) float f32x4;

__device__ __forceinline__ unsigned short f2bf(float f) {
    unsigned u = __builtin_bit_cast(unsigned, f);
    unsigned r = u + 0x7fffu + ((u >> 16) & 1u);
    return (unsigned short)(r >> 16);
}
__device__ __forceinline__ float bf2f(unsigned short v) {
    return __builtin_bit_cast(float, (unsigned)v << 16);
}
__device__ __forceinline__ float bfbits_lo(unsigned v) {
    return __builtin_bit_cast(float, (unsigned)(v << 16));
}
__device__ __forceinline__ float bfbits_hi(unsigned v) {
    return __builtin_bit_cast(float, v & 0xffff0000u);
}
__device__ __forceinline__ float sigmoidf_(float x) { return 1.f / (1.f + __expf(-x)); }
__device__ __forceinline__ float tanhf_(float x) { return 2.f / (1.f + __expf(-2.f * x)) - 1.f; }

// ---------------- prep: weights -> fragment-major bf16 ----------------
// Wp[nt][kk][lane][i] = W[k][n], k = kk*32 + (lane>>4)*8 + i, n = nt*16 + (lane&15)
__global__ void prep_w(const float* __restrict__ W, unsigned short* __restrict__ Wp, int NT) {
    int tid = blockIdx.x * 256 + threadIdx.x;
    int total = NT * 8 * 64;
    if (tid >= total) return;
    int l = tid & 63, kk = (tid >> 6) & 7, nt = tid >> 9;
    int n = nt * 16 + (l & 15);
    int k0 = kk * 32 + (l >> 4) * 8;
    int N = NT * 16;
    unsigned short v[8];
#pragma unroll
    for (int i = 0; i < 8; i++) v[i] = f2bf(W[(size_t)(k0 + i) * N + n]);
    uint4 o;
    o.x = (unsigned)v[0] | ((unsigned)v[1] << 16);
    o.y = (unsigned)v[2] | ((unsigned)v[3] << 16);
    o.z = (unsigned)v[4] | ((unsigned)v[5] << 16);
    o.w = (unsigned)v[6] | ((unsigned)v[7] << 16);
    *(uint4*)(Wp + (size_t)tid * 8) = o;
}

__global__ void prep_decay(const float* __restrict__ x, float* __restrict__ dec, int n) {
    int i = blockIdx.x * 256 + threadIdx.x;
    if (i < n) dec[i] = 1.f / __logf(2.718281828459045f + x[(size_t)i * H_ + (H_ - 1)]);
}

// ---------------- xg GEMM body (unchanged) ----------------
template <bool SRCF32>
__device__ void gemm_body(const void* __restrict__ src, const unsigned short* __restrict__ Wp,
                          const float* __restrict__ bias, unsigned short* __restrict__ xgp,
                          int chunk, short* Albs) {
    const int tid = threadIdx.x;
    const int bx = blockIdx.x;
    const int by = blockIdx.y;
    const int r0 = bx * 128;
    const int t_loc = r0 >> 8;
    const int b0 = r0 & 255;
    const int sg = chunk * CHUNK + t_loc;
    {
        const int m = tid >> 1, kh = tid & 1;
        const size_t rowbase = ((size_t)(b0 + m) * S_ + sg) * H_ + kh * 128;
        if constexpr (SRCF32) {
            const float* p = (const float*)src + rowbase;
#pragma unroll
            for (int jo = 0; jo < 16; jo++) {
                int k = kh * 128 + jo * 8;
                float4 a = *(const float4*)(p + jo * 8);
                float4 b = *(const float4*)(p + jo * 8 + 4);
                int slot = ((m >> 4) * 8 + (k >> 5)) * 64 + ((m & 15) | (((k >> 3) & 3) << 4));
                uint4 o;
                o.x = (unsigned)f2bf(a.x) | ((unsigned)f2bf(a.y) << 16);
                o.y = (unsigned)f2bf(a.z) | ((unsigned)f2bf(a.w) << 16);
                o.z = (unsigned)f2bf(b.x) | ((unsigned)f2bf(b.y) << 16);
                o.w = (unsigned)f2bf(b.z) | ((unsigned)f2bf(b.w) << 16);
                *(uint4*)&Albs[slot * 8] = o;
            }
        } else {
            const unsigned short* p = (const unsigned short*)src + rowbase;
#pragma unroll
            for (int jo = 0; jo < 16; jo++) {
                int k = kh * 128 + jo * 8;
                uint4 o = *(const uint4*)(p + jo * 8);
                int slot = ((m >> 4) * 8 + (k >> 5)) * 64 + ((m & 15) | (((k >> 3) & 3) << 4));
                *(uint4*)&Albs[slot * 8] = o;
            }
        }
    }
    __syncthreads();
    const int w = tid >> 6, l = tid & 63;
    const int wm = w >> 1, wn = w & 1;
    const int col = l & 15;
    float bv[4];
#pragma unroll
    for (int q = 0; q < 4; q++) bv[q] = bias[(by * 8 + wn * 4 + q) * 16 + col];
    f32x4 acc[4][4];
#pragma unroll
    for (int mi = 0; mi < 4; mi++)
#pragma unroll
        for (int q = 0; q < 4; q++) {
            acc[mi][q][0] = bv[q]; acc[mi][q][1] = bv[q];
            acc[mi][q][2] = bv[q]; acc[mi][q][3] = bv[q];
        }
    const bf16x8* Wp8 = (const bf16x8*)Wp;
#pragma unroll
    for (int kk = 0; kk < 8; kk++) {
        bf16x8 af[4], bfr[4];
#pragma unroll
        for (int mi = 0; mi < 4; mi++)
            af[mi] = *(const bf16x8*)&Albs[(((wm * 4 + mi) * 8 + kk) * 64 + l) * 8];
#pragma unroll
        for (int q = 0; q < 4; q++)
            bfr[q] = Wp8[((size_t)(by * 8 + wn * 4 + q) * 8 + kk) * 64 + l];
#pragma unroll
        for (int mi = 0; mi < 4; mi++)
#pragma unroll
            for (int q = 0; q < 4; q++)
                acc[mi][q] = __builtin_amdgcn_mfma_f32_16x16x32_bf16(af[mi], bfr[q], acc[mi][q], 0, 0, 0);
    }
    const int rblk0 = r0 >> 4;
#pragma unroll
    for (int mi = 0; mi < 4; mi++) {
        int rowblk = rblk0 + wm * 4 + mi;
#pragma unroll
        for (int q = 0; q < 4; q++) {
            int qg = by * 8 + wn * 4 + q;
            uint2 o;
            o.x = (unsigned)f2bf(acc[mi][q][0]) | ((unsigned)f2bf(acc[mi][q][1]) << 16);
            o.y = (unsigned)f2bf(acc[mi][q][2]) | ((unsigned)f2bf(acc[mi][q][3]) << 16);
            *(uint2*)&xgp[(((size_t)rowblk * 64 + qg) * 64 + l) * 4] = o;
        }
    }
}

__global__ __launch_bounds__(256) void gemm_dual(const float* __restrict__ x,
                                                 const unsigned short* __restrict__ y0bf,
                                                 const unsigned short* __restrict__ Wp0,
                                                 const float* __restrict__ bias0,
                                                 const unsigned short* __restrict__ Wp1,
                                                 const float* __restrict__ bias1,
                                                 unsigned short* __restrict__ xgpA,
                                                 unsigned short* __restrict__ xgpB, int c0, int c1) {
    extern __shared__ short Albs[];  // 64 KB
    if (blockIdx.z == 0) {
        if (c0 < 0) return;
        gemm_body<true>(x, Wp0, bias0, xgpA, c0, Albs);
    } else {
        if (c1 < 0) return;
        gemm_body<false>(y0bf, Wp1, bias1, xgpB, c1, Albs);
    }
}

// ---------------- recurrent scan: 8 waves, 2 col-tiles/wave (halved LDS broadcast) ------
// 32 WGs (16/layer), 512 thr (8 waves). Wave w owns col-tiles {2w, 2w+1}: each hf/cf
// ds_read feeds 10 MFMAs (2 csacc + 8 gacc), halving the 16x-redundant h/c broadcast
// (256->128 KB/step/WG). Wh AND Wd stream through a 2-parity VGPR buffer with 2-batch
// lookahead (compiler-counted vmcnt). h/c in LDS parity double buffer -> one lgkm-only
// barrier/step. EW uses v_cvt_pk_bf16_f32.
template <bool ISL0>
__device__ void rec_run(const unsigned short* __restrict__ xgp, const bf16x8* __restrict__ Whp8,
                        const bf16x8* __restrict__ Wdp8, const float* __restrict__ bd,
                        const float* __restrict__ dec_in, void* __restrict__ yout,
                        float* __restrict__ dec_out, unsigned short* __restrict__ h_state,
                        float* __restrict__ c_state, int chunk, int bblk, char* smem) {
    const int tid = threadIdx.x;         // 0..511
    const int w = tid >> 6, l = tid & 63;
    const int lgrp = l >> 4, col = l & 15;
    const int b0 = bblk * 16;
    const int ct0 = 2 * w, ct1 = 2 * w + 1;
    const int n0 = ct0 * 16 + col, n1 = ct1 * 16 + col;
    const float bdv[2] = {bd[n0], bd[n1]};

    float creg[2][4];
    {
        short* hb0 = (short*)smem;            // parity 0 h
        short* cb0 = (short*)(smem + 8192);   // parity 0 c
        if (chunk == 0) {
#pragma unroll
            for (int j = 0; j < 2; j++)
#pragma unroll
                for (int r = 0; r < 4; r++) creg[j][r] = 0.f;
            for (int i = tid; i < 4096; i += 512) { hb0[i] = 0; cb0[i] = 0; }
        } else {
#pragma unroll
            for (int i = 0; i < 8; i++) {
                int idx = tid + i * 512;
                int row = idx >> 8, nn = idx & 255;
                int sw = nn ^ ((row & 7) << 3);
                hb0[row * 256 + sw] = (short)h_state[(size_t)(b0 + row) * H_ + nn];
                cb0[row * 256 + sw] = (short)f2bf(c_state[(size_t)(b0 + row) * H_ + nn]);
            }
#pragma unroll
            for (int j = 0; j < 2; j++)
#pragma unroll
                for (int r = 0; r < 4; r++)
                    creg[j][r] = c_state[(size_t)(b0 + lgrp * 4 + r) * H_ + (j ? n1 : n0)];
        }
    }
    const uint2* xg8 = (const uint2*)xgp;
    uint2 xc[2][4], xn[2][4];
#pragma unroll
    for (int j = 0; j < 2; j++)
#pragma unroll
        for (int q = 0; q < 4; q++)
            xc[j][q] = xg8[((size_t)bblk * 64 + (q * 16 + 2 * w + j)) * 64 + l];
    float dn[4];
#pragma unroll
    for (int r = 0; r < 4; r++)
        dn[r] = dec_in[(size_t)(b0 + lgrp * 4 + r) * S_ + chunk * CHUNK];
    __syncthreads();  // chunk-start full barrier (staging visible)

    // 2-parity stream buffer: [par][j*4+q] Wh frags + [par][j] Wd frags.
    bf16x8 wfb[2][8], wdb[2][2];
#pragma unroll
    for (int p = 0; p < 2; p++)
#pragma unroll
        for (int j = 0; j < 2; j++) {
#pragma unroll
            for (int q = 0; q < 4; q++)
                wfb[p][j * 4 + q] = Whp8[((size_t)(q * 16 + 2 * w + j) * 8 + p) * 64 + l];
            wdb[p][j] = Wdp8[((size_t)(2 * w + j) * 8 + p) * 64 + l];
        }

#pragma unroll 1
    for (int t = 0; t < CHUNK; ++t) {
        const int tg = chunk * CHUNK + t;
        const int par = t & 1;
        const short* hb = (const short*)(smem + par * 16384);
        const short* cb = (const short*)(smem + par * 16384 + 8192);
        short* hx = (short*)(smem + (par ^ 1) * 16384);
        short* cx = (short*)(smem + (par ^ 1) * 16384 + 8192);
        // SGPR-side launder: weight loads formally t-variant (no LICM hoist)
        const bf16x8 *WhpT, *WdpT;
        {
            unsigned long long tz = 0;
            asm volatile("" : "+s"(tz));
            WhpT = (const bf16x8*)((const char*)Whp8 + tz);
            WdpT = (const bf16x8*)((const char*)Wdp8 + tz);
        }
        float dcur[4];
#pragma unroll
        for (int r = 0; r < 4; r++) dcur[r] = dn[r];
        f32x4 csacc[2];
        f32x4 gacc[2][4];
#pragma unroll
        for (int j = 0; j < 2; j++) {
            csacc[j][0] = 0.f; csacc[j][1] = 0.f; csacc[j][2] = 0.f; csacc[j][3] = 0.f;
#pragma unroll
            for (int q = 0; q < 4; q++) {
                uint2 v = xc[j][q];
                gacc[j][q][0] = bfbits_lo(v.x);
                gacc[j][q][1] = bfbits_hi(v.x);
                gacc[j][q][2] = bfbits_lo(v.y);
                gacc[j][q][3] = bfbits_hi(v.y);
            }
        }
#pragma unroll
        for (int kk = 0; kk < 8; kk++) {
            const int cur = kk & 1;
            // one hf/cf read feeds 10 MFMAs (2 col-tiles)
            const int ha = col * 256 + ((kk * 32 + lgrp * 8) ^ ((col & 7) << 3));
            bf16x8 hf = *(const bf16x8*)&hb[ha];
            bf16x8 cf = *(const bf16x8*)&cb[ha];
#pragma unroll
            for (int j = 0; j < 2; j++) {
                csacc[j] = __builtin_amdgcn_mfma_f32_16x16x32_bf16(cf, wdb[cur][j], csacc[j], 0, 0, 0);
#pragma unroll
                for (int q = 0; q < 4; q++)
                    gacc[j][q] = __builtin_amdgcn_mfma_f32_16x16x32_bf16(hf, wfb[cur][j * 4 + q],
                                                                         gacc[j][q], 0, 0, 0);
            }
            // refill cur's parity with batch kk+2 (kk=6 -> next step's 0, kk=7 -> next 1)
            const int kn2 = (kk + 2) & 7;
#pragma unroll
            for (int j = 0; j < 2; j++) {
#pragma unroll
                for (int q = 0; q < 4; q++)
                    wfb[cur][j * 4 + q] = WhpT[((size_t)(q * 16 + 2 * w + j) * 8 + kn2) * 64 + l];
                wdb[cur][j] = WdpT[((size_t)(2 * w + j) * 8 + kn2) * 64 + l];
            }
        }
        // prefetch next step's xg + dec (EW below hides latency; port stays busy)
        const int tn = (t + 1 < CHUNK) ? t + 1 : t;
        {
            int rb = tn * 16 + bblk;
#pragma unroll
            for (int j = 0; j < 2; j++)
#pragma unroll
                for (int q = 0; q < 4; q++)
                    xn[j][q] = xg8[((size_t)rb * 64 + (q * 16 + 2 * w + j)) * 64 + l];
            int tgn = chunk * CHUNK + tn;
#pragma unroll
            for (int r = 0; r < 4; r++)
                dn[r] = dec_in[(size_t)(b0 + lgrp * 4 + r) * S_ + tgn];
        }
        // EW (register-only) + LDS writes to the OTHER parity + global stores
#pragma unroll
        for (int j = 0; j < 2; j++) {
            const int n = j ? n1 : n0;
#pragma unroll
            for (int r = 0; r < 4; r++) {
                int row = lgrp * 4 + r;
                float cs = tanhf_(csacc[j][r] + bdv[j]);
                float cadj = creg[j][r] - cs + cs * dcur[r];
                float iv = sigmoidf_(gacc[j][0][r]);
                float fv = sigmoidf_(gacc[j][1][r]);
                float ov = sigmoidf_(gacc[j][2][r]);
                float cd = tanhf_(gacc[j][3][r]);
                float cn = fv * cadj + iv * cd;
                float hn = ov * tanhf_(cn);
                creg[j][r] = cn;
                int sw = n ^ ((row & 7) << 3);
                unsigned hc;  // packed {bf16(cn) hi, bf16(hn) lo}, RTN
                asm("v_cvt_pk_bf16_f32 %0, %1, %2" : "=v"(hc) : "v"(hn), "v"(cn));
                unsigned short hnb = (unsigned short)hc;
                hx[row * 256 + sw] = (short)hnb;
                cx[row * 256 + sw] = (short)(hc >> 16);
                size_t yi = ((size_t)(b0 + row) * S_ + tg) * H_ + n;
                if constexpr (ISL0) {
                    ((unsigned short*)yout)[yi] = hnb;
                    if (w == 7 && j == 1 && col == 15)
                        dec_out[(size_t)(b0 + row) * S_ + tg] =
                            1.f / __logf(2.718281828459045f + hn);
                } else {
                    ((float*)yout)[yi] = hn;
                }
                if (t == CHUNK - 1) {
                    h_state[(size_t)(b0 + row) * H_ + n] = hnb;
                    c_state[(size_t)(b0 + row) * H_ + n] = cn;
                }
            }
        }
        // SINGLE barrier per step: publish LDS writes (lgkm only — no VMEM drain).
        asm volatile("s_waitcnt lgkmcnt(0)" ::: "memory");
        __builtin_amdgcn_s_barrier();
        __builtin_amdgcn_sched_barrier(0);
#pragma unroll
        for (int j = 0; j < 2; j++)
#pragma unroll
            for (int q = 0; q < 4; q++) xc[j][q] = xn[j][q];
    }
}

__global__ __launch_bounds__(512, 2) void rec_fused(
    const unsigned short* __restrict__ xgpA, const unsigned short* __restrict__ Whp0,
    const unsigned short* __restrict__ Wdp0, const float* __restrict__ bd0,
    const float* __restrict__ dec0, unsigned short* __restrict__ y0bf,
    float* __restrict__ dec1, unsigned short* __restrict__ hs0, float* __restrict__ cs0,
    const unsigned short* __restrict__ xgpB, const unsigned short* __restrict__ Whp1,
    const unsigned short* __restrict__ Wdp1, const float* __restrict__ bd1,
    float* __restrict__ y1, unsigned short* __restrict__ hs1, float* __restrict__ cs1,
    int c0, int c1) {
    extern __shared__ char smem[];
    int lay = blockIdx.x >> 4, bblk = blockIdx.x & 15;
    if (lay == 0) {
        if (c0 < 0) return;
        rec_run<true>(xgpA, (const bf16x8*)Whp0, (const bf16x8*)Wdp0, bd0, dec0, y0bf, dec1,
                      hs0, cs0, c0, bblk, smem);
    } else {
        if (c1 < 0) return;
        rec_run<false>(xgpB, (const bf16x8*)Whp1, (const bf16x8*)Wdp1, bd1, dec1, y1, nullptr,
                       hs1, cs1, c1, bblk, smem);
    }
}

__global__ void copy_tail(const unsigned short* __restrict__ h0, const float* __restrict__ c0,
                          const unsigned short* __restrict__ h1, const float* __restrict__ c1,
                          float* __restrict__ out) {
    int i = blockIdx.x * 256 + threadIdx.x;
    if (i >= 4 * 65536) return;
    int which = i >> 16, j = i & 65535;
    float v = which == 0 ? bf2f(h0[j]) : which == 1 ? c0[j] : which == 2 ? bf2f(h1[j]) : c1[j];
    out[i] = v;
}

extern "C" void kernel_launch(void* const* d_in, const int* in_sizes, int n_in, void* d_out,
                              int out_size, void* d_ws, size_t ws_size, hipStream_t stream) {
    (void)in_sizes; (void)n_in; (void)out_size; (void)ws_size;
    const float* x   = (const float*)d_in[0];
    const float* Wx0 = (const float*)d_in[1];
    const float* Wh0 = (const float*)d_in[2];
    const float* b0  = (const float*)d_in[3];
    const float* Wd0 = (const float*)d_in[4];
    const float* bd0 = (const float*)d_in[5];
    const float* Wx1 = (const float*)d_in[6];
    const float* Wh1 = (const float*)d_in[7];
    const float* b1  = (const float*)d_in[8];
    const float* Wd1 = (const float*)d_in[9];
    const float* bd1 = (const float*)d_in[10];

    char* ws = (char*)d_ws;
    size_t off = 0;
    auto take = [&](size_t bytes) { void* p = ws + off; off += (bytes + 255) & ~(size_t)255; return p; };
    unsigned short* wxp0 = (unsigned short*)take(524288);
    unsigned short* whp0 = (unsigned short*)take(524288);
    unsigned short* wdp0 = (unsigned short*)take(131072);
    unsigned short* wxp1 = (unsigned short*)take(524288);
    unsigned short* whp1 = (unsigned short*)take(524288);
    unsigned short* wdp1 = (unsigned short*)take(131072);
    float* dec0 = (float*)take(524288);
    float* dec1 = (float*)take(524288);
    unsigned short* hs0 = (unsigned short*)take(131072);
    float* cs0 = (float*)take(262144);
    unsigned short* hs1 = (unsigned short*)take(131072);
    float* cs1 = (float*)take(262144);
    unsigned short* y0bf = (unsigned short*)take(67108864);
    unsigned short* xgpA = (unsigned short*)take(16777216);
    unsigned short* xgpB = (unsigned short*)take(16777216);

    const size_t smem_rec = 32768;  // h/c parity double buffer
    (void)hipFuncSetAttribute(reinterpret_cast<const void*>(&rec_fused),
                              hipFuncAttributeMaxDynamicSharedMemorySize, (int)smem_rec);
    (void)hipFuncSetAttribute(reinterpret_cast<const void*>(&gemm_dual),
                              hipFuncAttributeMaxDynamicSharedMemorySize, 65536);

    prep_w<<<128, 256, 0, stream>>>(Wx0, wxp0, 64);
    prep_w<<<128, 256, 0, stream>>>(Wh0, whp0, 64);
    prep_w<<<32, 256, 0, stream>>>(Wd0, wdp0, 16);
    prep_w<<<128, 256, 0, stream>>>(Wx1, wxp1, 64);
    prep_w<<<128, 256, 0, stream>>>(Wh1, whp1, 64);
    prep_w<<<32, 256, 0, stream>>>(Wd1, wdp1, 16);
    prep_decay<<<512, 256, 0, stream>>>(x, dec0, B_ * S_);

    float* y1 = (float*)d_out;
    for (int s = 0; s <= NCHUNK; ++s) {
        int c0 = (s < NCHUNK) ? s : -1;
        int c1 = (s >= 1) ? s - 1 : -1;
        gemm_dual<<<dim3(64, 8, 2), 256, 65536, stream>>>(x, y0bf, wxp0, b0, wxp1, b1,
                                                          xgpA, xgpB, c0, c1);
        rec_fused<<<32, 512, smem_rec, stream>>>(xgpA, whp0, wdp0, bd0, dec0, y0bf, dec1,
                                                 hs0, cs0, xgpB, whp1, wdp1, bd1, y1,
                                                 hs1, cs1, c0, c1);
    }
    copy_tail<<<1024, 256, 0, stream>>>(hs0, cs0, hs1, cs1, y1 + (size_t)B_ * S_ * H_);
}

// Round 14
// 5120.318 us; speedup vs baseline: 1.0924x; 1.0924x over previous
//
#include <hip/hip_runtime.h>
#include <stdint.h>

#define B_ 256
#define S_ 512
#define H_ 256
#define G_ 1024
#define CHUNK 32
#define NCHUNK (S_ / CHUNK)

typedef __attribute__((ext_vector_type(8))) short bf16x8;
typedef __attribute__((ext_vector_type(4))) float f32x4;

__device__ __forceinline__ unsigned short f2bf(float f) {
    unsigned u = __builtin_bit_cast(unsigned, f);
    unsigned r = u + 0x7fffu + ((u >> 16) & 1u);
    return (unsigned short)(r >> 16);
}
__device__ __forceinline__ float bf2f(unsigned short v) {
    return __builtin_bit_cast(float, (unsigned)v << 16);
}
__device__ __forceinline__ float bfbits_lo(unsigned v) {
    return __builtin_bit_cast(float, (unsigned)(v << 16));
}
__device__ __forceinline__ float bfbits_hi(unsigned v) {
    return __builtin_bit_cast(float, v & 0xffff0000u);
}
__device__ __forceinline__ float sigmoidf_(float x) { return 1.f / (1.f + __expf(-x)); }
__device__ __forceinline__ float tanhf_(float x) { return 2.f / (1.f + __expf(-2.f * x)) - 1.f; }

// sched_barrier mask: ALU|VALU|SALU|MFMA|DS|DS_READ|DS_WRITE may cross; VMEM may NOT.
// Used to pin weight-load issue points so the scheduler can't sink them to just-before-use
// (which collapses the stream to 1 batch in flight — the R10-12 VGPR=64 signature).
#define SCHED_PIN_VMEM() __builtin_amdgcn_sched_barrier(0x38F)

// ---------------- prep: weights -> fragment-major bf16 ----------------
// Wp[nt][kk][lane][i] = W[k][n], k = kk*32 + (lane>>4)*8 + i, n = nt*16 + (lane&15)
__global__ void prep_w(const float* __restrict__ W, unsigned short* __restrict__ Wp, int NT) {
    int tid = blockIdx.x * 256 + threadIdx.x;
    int total = NT * 8 * 64;
    if (tid >= total) return;
    int l = tid & 63, kk = (tid >> 6) & 7, nt = tid >> 9;
    int n = nt * 16 + (l & 15);
    int k0 = kk * 32 + (l >> 4) * 8;
    int N = NT * 16;
    unsigned short v[8];
#pragma unroll
    for (int i = 0; i < 8; i++) v[i] = f2bf(W[(size_t)(k0 + i) * N + n]);
    uint4 o;
    o.x = (unsigned)v[0] | ((unsigned)v[1] << 16);
    o.y = (unsigned)v[2] | ((unsigned)v[3] << 16);
    o.z = (unsigned)v[4] | ((unsigned)v[5] << 16);
    o.w = (unsigned)v[6] | ((unsigned)v[7] << 16);
    *(uint4*)(Wp + (size_t)tid * 8) = o;
}

__global__ void prep_decay(const float* __restrict__ x, float* __restrict__ dec, int n) {
    int i = blockIdx.x * 256 + threadIdx.x;
    if (i < n) dec[i] = 1.f / __logf(2.718281828459045f + x[(size_t)i * H_ + (H_ - 1)]);
}

// ---------------- xg GEMM body (unchanged) ----------------
template <bool SRCF32>
__device__ void gemm_body(const void* __restrict__ src, const unsigned short* __restrict__ Wp,
                          const float* __restrict__ bias, unsigned short* __restrict__ xgp,
                          int chunk, short* Albs) {
    const int tid = threadIdx.x;
    const int bx = blockIdx.x;
    const int by = blockIdx.y;
    const int r0 = bx * 128;
    const int t_loc = r0 >> 8;
    const int b0 = r0 & 255;
    const int sg = chunk * CHUNK + t_loc;
    {
        const int m = tid >> 1, kh = tid & 1;
        const size_t rowbase = ((size_t)(b0 + m) * S_ + sg) * H_ + kh * 128;
        if constexpr (SRCF32) {
            const float* p = (const float*)src + rowbase;
#pragma unroll
            for (int jo = 0; jo < 16; jo++) {
                int k = kh * 128 + jo * 8;
                float4 a = *(const float4*)(p + jo * 8);
                float4 b = *(const float4*)(p + jo * 8 + 4);
                int slot = ((m >> 4) * 8 + (k >> 5)) * 64 + ((m & 15) | (((k >> 3) & 3) << 4));
                uint4 o;
                o.x = (unsigned)f2bf(a.x) | ((unsigned)f2bf(a.y) << 16);
                o.y = (unsigned)f2bf(a.z) | ((unsigned)f2bf(a.w) << 16);
                o.z = (unsigned)f2bf(b.x) | ((unsigned)f2bf(b.y) << 16);
                o.w = (unsigned)f2bf(b.z) | ((unsigned)f2bf(b.w) << 16);
                *(uint4*)&Albs[slot * 8] = o;
            }
        } else {
            const unsigned short* p = (const unsigned short*)src + rowbase;
#pragma unroll
            for (int jo = 0; jo < 16; jo++) {
                int k = kh * 128 + jo * 8;
                uint4 o = *(const uint4*)(p + jo * 8);
                int slot = ((m >> 4) * 8 + (k >> 5)) * 64 + ((m & 15) | (((k >> 3) & 3) << 4));
                *(uint4*)&Albs[slot * 8] = o;
            }
        }
    }
    __syncthreads();
    const int w = tid >> 6, l = tid & 63;
    const int wm = w >> 1, wn = w & 1;
    const int col = l & 15;
    float bv[4];
#pragma unroll
    for (int q = 0; q < 4; q++) bv[q] = bias[(by * 8 + wn * 4 + q) * 16 + col];
    f32x4 acc[4][4];
#pragma unroll
    for (int mi = 0; mi < 4; mi++)
#pragma unroll
        for (int q = 0; q < 4; q++) {
            acc[mi][q][0] = bv[q]; acc[mi][q][1] = bv[q];
            acc[mi][q][2] = bv[q]; acc[mi][q][3] = bv[q];
        }
    const bf16x8* Wp8 = (const bf16x8*)Wp;
#pragma unroll
    for (int kk = 0; kk < 8; kk++) {
        bf16x8 af[4], bfr[4];
#pragma unroll
        for (int mi = 0; mi < 4; mi++)
            af[mi] = *(const bf16x8*)&Albs[(((wm * 4 + mi) * 8 + kk) * 64 + l) * 8];
#pragma unroll
        for (int q = 0; q < 4; q++)
            bfr[q] = Wp8[((size_t)(by * 8 + wn * 4 + q) * 8 + kk) * 64 + l];
#pragma unroll
        for (int mi = 0; mi < 4; mi++)
#pragma unroll
            for (int q = 0; q < 4; q++)
                acc[mi][q] = __builtin_amdgcn_mfma_f32_16x16x32_bf16(af[mi], bfr[q], acc[mi][q], 0, 0, 0);
    }
    const int rblk0 = r0 >> 4;
#pragma unroll
    for (int mi = 0; mi < 4; mi++) {
        int rowblk = rblk0 + wm * 4 + mi;
#pragma unroll
        for (int q = 0; q < 4; q++) {
            int qg = by * 8 + wn * 4 + q;
            uint2 o;
            o.x = (unsigned)f2bf(acc[mi][q][0]) | ((unsigned)f2bf(acc[mi][q][1]) << 16);
            o.y = (unsigned)f2bf(acc[mi][q][2]) | ((unsigned)f2bf(acc[mi][q][3]) << 16);
            *(uint2*)&xgp[(((size_t)rowblk * 64 + qg) * 64 + l) * 4] = o;
        }
    }
}

__global__ __launch_bounds__(256) void gemm_dual(const float* __restrict__ x,
                                                 const unsigned short* __restrict__ y0bf,
                                                 const unsigned short* __restrict__ Wp0,
                                                 const float* __restrict__ bias0,
                                                 const unsigned short* __restrict__ Wp1,
                                                 const float* __restrict__ bias1,
                                                 unsigned short* __restrict__ xgpA,
                                                 unsigned short* __restrict__ xgpB, int c0, int c1) {
    extern __shared__ short Albs[];  // 64 KB
    if (blockIdx.z == 0) {
        if (c0 < 0) return;
        gemm_body<true>(x, Wp0, bias0, xgpA, c0, Albs);
    } else {
        if (c1 < 0) return;
        gemm_body<false>(y0bf, Wp1, bias1, xgpB, c1, Albs);
    }
}

// ---------------- recurrent scan: R12 + VMEM sched-pins ----------------
// 32 WGs (16/layer), 1024 thr (16 waves). Wave w owns col-tile w. Wh streams into a
// 2-parity VGPR buffer with 2-batch lookahead; a sched_barrier excluding VMEM after each
// refill block prevents the scheduler from sinking the loads to just-before-use, keeping
// ~8 loads in flight per wave. Wd chunk-resident. h/c LDS parity double buffer -> one
// lgkm-only barrier/step. EW uses v_cvt_pk_bf16_f32.
template <bool ISL0>
__device__ void rec_run(const unsigned short* __restrict__ xgp, const bf16x8* __restrict__ Whp8,
                        const bf16x8* __restrict__ Wdp8, const float* __restrict__ bd,
                        const float* __restrict__ dec_in, void* __restrict__ yout,
                        float* __restrict__ dec_out, unsigned short* __restrict__ h_state,
                        float* __restrict__ c_state, int chunk, int bblk, char* smem) {
    const int tid = threadIdx.x;         // 0..1023
    const int w = tid >> 6, l = tid & 63;
    const int lgrp = l >> 4, col = l & 15;
    const int b0 = bblk * 16;
    const int n = w * 16 + col;
    const float bdv = bd[n];

    // Wd tile resident in registers for the whole chunk (32 VGPR)
    bf16x8 wd[8];
#pragma unroll
    for (int kk = 0; kk < 8; kk++) wd[kk] = Wdp8[((size_t)w * 8 + kk) * 64 + l];

    float creg[4];
    {
        short* hb0 = (short*)smem;            // parity 0 h
        short* cb0 = (short*)(smem + 8192);   // parity 0 c
        if (chunk == 0) {
#pragma unroll
            for (int r = 0; r < 4; r++) creg[r] = 0.f;
            for (int i = tid; i < 4096; i += 1024) { hb0[i] = 0; cb0[i] = 0; }
        } else {
#pragma unroll
            for (int i = 0; i < 4; i++) {
                int idx = tid + i * 1024;
                int row = idx >> 8, nn = idx & 255;
                int sw = nn ^ ((row & 7) << 3);
                hb0[row * 256 + sw] = (short)h_state[(size_t)(b0 + row) * H_ + nn];
                cb0[row * 256 + sw] = (short)f2bf(c_state[(size_t)(b0 + row) * H_ + nn]);
            }
#pragma unroll
            for (int r = 0; r < 4; r++)
                creg[r] = c_state[(size_t)(b0 + lgrp * 4 + r) * H_ + n];
        }
    }
    const uint2* xg8 = (const uint2*)xgp;
    uint2 xc[4], xn[4];
#pragma unroll
    for (int q = 0; q < 4; q++)
        xc[q] = xg8[((size_t)bblk * 64 + (q * 16 + w)) * 64 + l];
    float dn[4];
#pragma unroll
    for (int r = 0; r < 4; r++)
        dn[r] = dec_in[(size_t)(b0 + lgrp * 4 + r) * S_ + chunk * CHUNK];
    __syncthreads();  // chunk-start full barrier (staging visible)

    // prologue: kk=0 batch -> parity 0, kk=1 batch -> parity 1 (2-deep from the start)
    bf16x8 wfb[2][4];
#pragma unroll
    for (int q = 0; q < 4; q++) wfb[0][q] = Whp8[((size_t)(q * 16 + w) * 8 + 0) * 64 + l];
#pragma unroll
    for (int q = 0; q < 4; q++) wfb[1][q] = Whp8[((size_t)(q * 16 + w) * 8 + 1) * 64 + l];
    SCHED_PIN_VMEM();

#pragma unroll 1
    for (int t = 0; t < CHUNK; ++t) {
        const int tg = chunk * CHUNK + t;
        const int par = t & 1;
        const short* hb = (const short*)(smem + par * 16384);
        const short* cb = (const short*)(smem + par * 16384 + 8192);
        short* hx = (short*)(smem + (par ^ 1) * 16384);
        short* cx = (short*)(smem + (par ^ 1) * 16384 + 8192);
        // SGPR-side launder: weight loads formally t-variant (no LICM hoist)
        const bf16x8* WhpT;
        {
            unsigned long long tz = 0;
            asm volatile("" : "+s"(tz));
            WhpT = (const bf16x8*)((const char*)Whp8 + tz);
        }
        float dcur[4];
#pragma unroll
        for (int r = 0; r < 4; r++) dcur[r] = dn[r];
        f32x4 csacc = {0.f, 0.f, 0.f, 0.f};
        f32x4 gacc[4];
#pragma unroll
        for (int q = 0; q < 4; q++) {
            uint2 v = xc[q];
            gacc[q][0] = bfbits_lo(v.x);
            gacc[q][1] = bfbits_hi(v.x);
            gacc[q][2] = bfbits_lo(v.y);
            gacc[q][3] = bfbits_hi(v.y);
        }
#pragma unroll
        for (int kk = 0; kk < 8; kk++) {
            const int cur = kk & 1;
            // MFMAs consume cur (its loads were issued two kk-iterations ago)
            const int ha = col * 256 + ((kk * 32 + lgrp * 8) ^ ((col & 7) << 3));
            bf16x8 hf = *(const bf16x8*)&hb[ha];
            bf16x8 cf = *(const bf16x8*)&cb[ha];
            csacc = __builtin_amdgcn_mfma_f32_16x16x32_bf16(cf, wd[kk], csacc, 0, 0, 0);
#pragma unroll
            for (int q = 0; q < 4; q++)
                gacc[q] = __builtin_amdgcn_mfma_f32_16x16x32_bf16(hf, wfb[cur][q], gacc[q], 0, 0, 0);
            // refill cur's parity with batch kk+2 (kk=6 -> next step's 0, kk=7 -> next 1),
            // then PIN: VMEM may not sink below this point (keeps ~8 loads in flight).
            const int kn2 = (kk + 2) & 7;
#pragma unroll
            for (int q = 0; q < 4; q++)
                wfb[cur][q] = WhpT[((size_t)(q * 16 + w) * 8 + kn2) * 64 + l];
            SCHED_PIN_VMEM();
        }
        // prefetch next step's xg + dec (EW below hides latency); pin their issue too.
        const int tn = (t + 1 < CHUNK) ? t + 1 : t;
        {
            int rb = tn * 16 + bblk;
#pragma unroll
            for (int q = 0; q < 4; q++)
                xn[q] = xg8[((size_t)rb * 64 + (q * 16 + w)) * 64 + l];
            int tgn = chunk * CHUNK + tn;
#pragma unroll
            for (int r = 0; r < 4; r++)
                dn[r] = dec_in[(size_t)(b0 + lgrp * 4 + r) * S_ + tgn];
        }
        SCHED_PIN_VMEM();
        // EW (register-only) + LDS writes to the OTHER parity + global stores
#pragma unroll
        for (int r = 0; r < 4; r++) {
            int row = lgrp * 4 + r;
            float cs = tanhf_(csacc[r] + bdv);
            float cadj = creg[r] - cs + cs * dcur[r];
            float iv = sigmoidf_(gacc[0][r]);
            float fv = sigmoidf_(gacc[1][r]);
            float ov = sigmoidf_(gacc[2][r]);
            float cd = tanhf_(gacc[3][r]);
            float cn = fv * cadj + iv * cd;
            float hn = ov * tanhf_(cn);
            creg[r] = cn;
            int sw = n ^ ((row & 7) << 3);
            unsigned hc;  // packed {bf16(cn) hi, bf16(hn) lo}, RTN in one instruction
            asm("v_cvt_pk_bf16_f32 %0, %1, %2" : "=v"(hc) : "v"(hn), "v"(cn));
            unsigned short hnb = (unsigned short)hc;
            hx[row * 256 + sw] = (short)hnb;
            cx[row * 256 + sw] = (short)(hc >> 16);
            size_t yi = ((size_t)(b0 + row) * S_ + tg) * H_ + n;
            if constexpr (ISL0) {
                ((unsigned short*)yout)[yi] = hnb;
                if (w == 15 && col == 15)
                    dec_out[(size_t)(b0 + row) * S_ + tg] = 1.f / __logf(2.718281828459045f + hn);
            } else {
                ((float*)yout)[yi] = hn;
            }
            if (t == CHUNK - 1) {
                h_state[(size_t)(b0 + row) * H_ + n] = hnb;
                c_state[(size_t)(b0 + row) * H_ + n] = cn;
            }
        }
        // SINGLE barrier per step: publish LDS writes (lgkm only — no VMEM drain).
        asm volatile("s_waitcnt lgkmcnt(0)" ::: "memory");
        __builtin_amdgcn_s_barrier();
        __builtin_amdgcn_sched_barrier(0);
#pragma unroll
        for (int q = 0; q < 4; q++) xc[q] = xn[q];
    }
}

__global__ __launch_bounds__(1024, 4) void rec_fused(
    const unsigned short* __restrict__ xgpA, const unsigned short* __restrict__ Whp0,
    const unsigned short* __restrict__ Wdp0, const float* __restrict__ bd0,
    const float* __restrict__ dec0, unsigned short* __restrict__ y0bf,
    float* __restrict__ dec1, unsigned short* __restrict__ hs0, float* __restrict__ cs0,
    const unsigned short* __restrict__ xgpB, const unsigned short* __restrict__ Whp1,
    const unsigned short* __restrict__ Wdp1, const float* __restrict__ bd1,
    float* __restrict__ y1, unsigned short* __restrict__ hs1, float* __restrict__ cs1,
    int c0, int c1) {
    extern __shared__ char smem[];
    int lay = blockIdx.x >> 4, bblk = blockIdx.x & 15;
    if (lay == 0) {
        if (c0 < 0) return;
        rec_run<true>(xgpA, (const bf16x8*)Whp0, (const bf16x8*)Wdp0, bd0, dec0, y0bf, dec1,
                      hs0, cs0, c0, bblk, smem);
    } else {
        if (c1 < 0) return;
        rec_run<false>(xgpB, (const bf16x8*)Whp1, (const bf16x8*)Wdp1, bd1, dec1, y1, nullptr,
                       hs1, cs1, c1, bblk, smem);
    }
}

__global__ void copy_tail(const unsigned short* __restrict__ h0, const float* __restrict__ c0,
                          const unsigned short* __restrict__ h1, const float* __restrict__ c1,
                          float* __restrict__ out) {
    int i = blockIdx.x * 256 + threadIdx.x;
    if (i >= 4 * 65536) return;
    int which = i >> 16, j = i & 65535;
    float v = which == 0 ? bf2f(h0[j]) : which == 1 ? c0[j] : which == 2 ? bf2f(h1[j]) : c1[j];
    out[i] = v;
}

extern "C" void kernel_launch(void* const* d_in, const int* in_sizes, int n_in, void* d_out,
                              int out_size, void* d_ws, size_t ws_size, hipStream_t stream) {
    (void)in_sizes; (void)n_in; (void)out_size; (void)ws_size;
    const float* x   = (const float*)d_in[0];
    const float* Wx0 = (const float*)d_in[1];
    const float* Wh0 = (const float*)d_in[2];
    const float* b0  = (const float*)d_in[3];
    const float* Wd0 = (const float*)d_in[4];
    const float* bd0 = (const float*)d_in[5];
    const float* Wx1 = (const float*)d_in[6];
    const float* Wh1 = (const float*)d_in[7];
    const float* b1  = (const float*)d_in[8];
    const float* Wd1 = (const float*)d_in[9];
    const float* bd1 = (const float*)d_in[10];

    char* ws = (char*)d_ws;
    size_t off = 0;
    auto take = [&](size_t bytes) { void* p = ws + off; off += (bytes + 255) & ~(size_t)255; return p; };
    unsigned short* wxp0 = (unsigned short*)take(524288);
    unsigned short* whp0 = (unsigned short*)take(524288);
    unsigned short* wdp0 = (unsigned short*)take(131072);
    unsigned short* wxp1 = (unsigned short*)take(524288);
    unsigned short* whp1 = (unsigned short*)take(524288);
    unsigned short* wdp1 = (unsigned short*)take(131072);
    float* dec0 = (float*)take(524288);
    float* dec1 = (float*)take(524288);
    unsigned short* hs0 = (unsigned short*)take(131072);
    float* cs0 = (float*)take(262144);
    unsigned short* hs1 = (unsigned short*)take(131072);
    float* cs1 = (float*)take(262144);
    unsigned short* y0bf = (unsigned short*)take(67108864);
    unsigned short* xgpA = (unsigned short*)take(16777216);
    unsigned short* xgpB = (unsigned short*)take(16777216);

    const size_t smem_rec = 32768;  // h/c parity double buffer
    (void)hipFuncSetAttribute(reinterpret_cast<const void*>(&rec_fused),
                              hipFuncAttributeMaxDynamicSharedMemorySize, (int)smem_rec);
    (void)hipFuncSetAttribute(reinterpret_cast<const void*>(&gemm_dual),
                              hipFuncAttributeMaxDynamicSharedMemorySize, 65536);

    prep_w<<<128, 256, 0, stream>>>(Wx0, wxp0, 64);
    prep_w<<<128, 256, 0, stream>>>(Wh0, whp0, 64);
    prep_w<<<32, 256, 0, stream>>>(Wd0, wdp0, 16);
    prep_w<<<128, 256, 0, stream>>>(Wx1, wxp1, 64);
    prep_w<<<128, 256, 0, stream>>>(Wh1, whp1, 64);
    prep_w<<<32, 256, 0, stream>>>(Wd1, wdp1, 16);
    prep_decay<<<512, 256, 0, stream>>>(x, dec0, B_ * S_);

    float* y1 = (float*)d_out;
    for (int s = 0; s <= NCHUNK; ++s) {
        int c0 = (s < NCHUNK) ? s : -1;
        int c1 = (s >= 1) ? s - 1 : -1;
        gemm_dual<<<dim3(64, 8, 2), 256, 65536, stream>>>(x, y0bf, wxp0, b0, wxp1, b1,
                                                          xgpA, xgpB, c0, c1);
        rec_fused<<<32, 1024, smem_rec, stream>>>(xgpA, whp0, wdp0, bd0, dec0, y0bf, dec1,
                                                  hs0, cs0, xgpB, whp1, wdp1, bd1, y1,
                                                  hs1, cs1, c0, c1);
    }
    copy_tail<<<1024, 256, 0, stream>>>(hs0, cs0, hs1, cs1, y1 + (size_t)B_ * S_ * H_);
}

// Round 15
// 4882.952 us; speedup vs baseline: 1.1455x; 1.0486x over previous
//
#include <hip/hip_runtime.h>
#include <stdint.h>

#define B_ 256
#define S_ 512
#define H_ 256
#define G_ 1024
#define CHUNK 32
#define NCHUNK (S_ / CHUNK)

typedef __attribute__((ext_vector_type(8))) short bf16x8;
typedef __attribute__((ext_vector_type(4))) float f32x4;

__device__ __forceinline__ unsigned short f2bf(float f) {
    unsigned u = __builtin_bit_cast(unsigned, f);
    unsigned r = u + 0x7fffu + ((u >> 16) & 1u);
    return (unsigned short)(r >> 16);
}
__device__ __forceinline__ float bf2f(unsigned short v) {
    return __builtin_bit_cast(float, (unsigned)v << 16);
}
__device__ __forceinline__ float bfbits_lo(unsigned v) {
    return __builtin_bit_cast(float, (unsigned)(v << 16));
}
__device__ __forceinline__ float bfbits_hi(unsigned v) {
    return __builtin_bit_cast(float, v & 0xffff0000u);
}
__device__ __forceinline__ float sigmoidf_(float x) { return 1.f / (1.f + __expf(-x)); }
__device__ __forceinline__ float tanhf_(float x) { return 2.f / (1.f + __expf(-2.f * x)) - 1.f; }

// ---------------- prep: weights -> fragment-major bf16 ----------------
// Wp[nt][kk][lane][i] = W[k][n], k = kk*32 + (lane>>4)*8 + i, n = nt*16 + (lane&15)
__global__ void prep_w(const float* __restrict__ W, unsigned short* __restrict__ Wp, int NT) {
    int tid = blockIdx.x * 256 + threadIdx.x;
    int total = NT * 8 * 64;
    if (tid >= total) return;
    int l = tid & 63, kk = (tid >> 6) & 7, nt = tid >> 9;
    int n = nt * 16 + (l & 15);
    int k0 = kk * 32 + (l >> 4) * 8;
    int N = NT * 16;
    unsigned short v[8];
#pragma unroll
    for (int i = 0; i < 8; i++) v[i] = f2bf(W[(size_t)(k0 + i) * N + n]);
    uint4 o;
    o.x = (unsigned)v[0] | ((unsigned)v[1] << 16);
    o.y = (unsigned)v[2] | ((unsigned)v[3] << 16);
    o.z = (unsigned)v[4] | ((unsigned)v[5] << 16);
    o.w = (unsigned)v[6] | ((unsigned)v[7] << 16);
    *(uint4*)(Wp + (size_t)tid * 8) = o;
}

__global__ void prep_decay(const float* __restrict__ x, float* __restrict__ dec, int n) {
    int i = blockIdx.x * 256 + threadIdx.x;
    if (i < n) dec[i] = 1.f / __logf(2.718281828459045f + x[(size_t)i * H_ + (H_ - 1)]);
}

// ---------------- xg GEMM body (unchanged) ----------------
template <bool SRCF32>
__device__ void gemm_body(const void* __restrict__ src, const unsigned short* __restrict__ Wp,
                          const float* __restrict__ bias, unsigned short* __restrict__ xgp,
                          int chunk, short* Albs) {
    const int tid = threadIdx.x;
    const int bx = blockIdx.x;
    const int by = blockIdx.y;
    const int r0 = bx * 128;
    const int t_loc = r0 >> 8;
    const int b0 = r0 & 255;
    const int sg = chunk * CHUNK + t_loc;
    {
        const int m = tid >> 1, kh = tid & 1;
        const size_t rowbase = ((size_t)(b0 + m) * S_ + sg) * H_ + kh * 128;
        if constexpr (SRCF32) {
            const float* p = (const float*)src + rowbase;
#pragma unroll
            for (int jo = 0; jo < 16; jo++) {
                int k = kh * 128 + jo * 8;
                float4 a = *(const float4*)(p + jo * 8);
                float4 b = *(const float4*)(p + jo * 8 + 4);
                int slot = ((m >> 4) * 8 + (k >> 5)) * 64 + ((m & 15) | (((k >> 3) & 3) << 4));
                uint4 o;
                o.x = (unsigned)f2bf(a.x) | ((unsigned)f2bf(a.y) << 16);
                o.y = (unsigned)f2bf(a.z) | ((unsigned)f2bf(a.w) << 16);
                o.z = (unsigned)f2bf(b.x) | ((unsigned)f2bf(b.y) << 16);
                o.w = (unsigned)f2bf(b.z) | ((unsigned)f2bf(b.w) << 16);
                *(uint4*)&Albs[slot * 8] = o;
            }
        } else {
            const unsigned short* p = (const unsigned short*)src + rowbase;
#pragma unroll
            for (int jo = 0; jo < 16; jo++) {
                int k = kh * 128 + jo * 8;
                uint4 o = *(const uint4*)(p + jo * 8);
                int slot = ((m >> 4) * 8 + (k >> 5)) * 64 + ((m & 15) | (((k >> 3) & 3) << 4));
                *(uint4*)&Albs[slot * 8] = o;
            }
        }
    }
    __syncthreads();
    const int w = tid >> 6, l = tid & 63;
    const int wm = w >> 1, wn = w & 1;
    const int col = l & 15;
    float bv[4];
#pragma unroll
    for (int q = 0; q < 4; q++) bv[q] = bias[(by * 8 + wn * 4 + q) * 16 + col];
    f32x4 acc[4][4];
#pragma unroll
    for (int mi = 0; mi < 4; mi++)
#pragma unroll
        for (int q = 0; q < 4; q++) {
            acc[mi][q][0] = bv[q]; acc[mi][q][1] = bv[q];
            acc[mi][q][2] = bv[q]; acc[mi][q][3] = bv[q];
        }
    const bf16x8* Wp8 = (const bf16x8*)Wp;
#pragma unroll
    for (int kk = 0; kk < 8; kk++) {
        bf16x8 af[4], bfr[4];
#pragma unroll
        for (int mi = 0; mi < 4; mi++)
            af[mi] = *(const bf16x8*)&Albs[(((wm * 4 + mi) * 8 + kk) * 64 + l) * 8];
#pragma unroll
        for (int q = 0; q < 4; q++)
            bfr[q] = Wp8[((size_t)(by * 8 + wn * 4 + q) * 8 + kk) * 64 + l];
#pragma unroll
        for (int mi = 0; mi < 4; mi++)
#pragma unroll
            for (int q = 0; q < 4; q++)
                acc[mi][q] = __builtin_amdgcn_mfma_f32_16x16x32_bf16(af[mi], bfr[q], acc[mi][q], 0, 0, 0);
    }
    const int rblk0 = r0 >> 4;
#pragma unroll
    for (int mi = 0; mi < 4; mi++) {
        int rowblk = rblk0 + wm * 4 + mi;
#pragma unroll
        for (int q = 0; q < 4; q++) {
            int qg = by * 8 + wn * 4 + q;
            uint2 o;
            o.x = (unsigned)f2bf(acc[mi][q][0]) | ((unsigned)f2bf(acc[mi][q][1]) << 16);
            o.y = (unsigned)f2bf(acc[mi][q][2]) | ((unsigned)f2bf(acc[mi][q][3]) << 16);
            *(uint2*)&xgp[(((size_t)rowblk * 64 + qg) * 64 + l) * 4] = o;
        }
    }
}

__global__ __launch_bounds__(256) void gemm_dual(const float* __restrict__ x,
                                                 const unsigned short* __restrict__ y0bf,
                                                 const unsigned short* __restrict__ Wp0,
                                                 const float* __restrict__ bias0,
                                                 const unsigned short* __restrict__ Wp1,
                                                 const float* __restrict__ bias1,
                                                 unsigned short* __restrict__ xgpA,
                                                 unsigned short* __restrict__ xgpB, int c0, int c1) {
    extern __shared__ short Albs[];  // 64 KB
    if (blockIdx.z == 0) {
        if (c0 < 0) return;
        gemm_body<true>(x, Wp0, bias0, xgpA, c0, Albs);
    } else {
        if (c1 < 0) return;
        gemm_body<false>(y0bf, Wp1, bias1, xgpB, c1, Albs);
    }
}

// ---------------- recurrent scan: VGPR weight streaming + single barrier/step ----------
// (R11 configuration — best measured: rec 266 µs. 32 WGs (16/layer), 1024 thr (16 waves).
// Wave w owns col-tile w. Wh streams into a 2-parity VGPR buffer (compiler-counted vmcnt
// waits, 1-deep rotation); Wd chunk-resident in VGPRs. h/c in LDS parity double buffer:
// step t reads parity t&1, writes (t&1)^1 -> ONE lgkm-only barrier/step. EW register-only,
// v_cvt_pk_bf16_f32 for (h,c)->bf16. Final chunk writes the f32 h/c tail of d_out
// directly (copy_tail folded in).
template <bool ISL0>
__device__ void rec_run(const unsigned short* __restrict__ xgp, const bf16x8* __restrict__ Whp8,
                        const bf16x8* __restrict__ Wdp8, const float* __restrict__ bd,
                        const float* __restrict__ dec_in, void* __restrict__ yout,
                        float* __restrict__ dec_out, unsigned short* __restrict__ h_state,
                        float* __restrict__ c_state, float* __restrict__ tail,
                        int chunk, int bblk, char* smem) {
    const int tid = threadIdx.x;         // 0..1023
    const int w = tid >> 6, l = tid & 63;
    const int lgrp = l >> 4, col = l & 15;
    const int b0 = bblk * 16;
    const int n = w * 16 + col;
    const float bdv = bd[n];

    // Wd tile resident in registers for the whole chunk (32 VGPR)
    bf16x8 wd[8];
#pragma unroll
    for (int kk = 0; kk < 8; kk++) wd[kk] = Wdp8[((size_t)w * 8 + kk) * 64 + l];

    float creg[4];
    {
        short* hb0 = (short*)smem;            // parity 0 h
        short* cb0 = (short*)(smem + 8192);   // parity 0 c
        if (chunk == 0) {
#pragma unroll
            for (int r = 0; r < 4; r++) creg[r] = 0.f;
            for (int i = tid; i < 4096; i += 1024) { hb0[i] = 0; cb0[i] = 0; }
        } else {
#pragma unroll
            for (int i = 0; i < 4; i++) {
                int idx = tid + i * 1024;
                int row = idx >> 8, nn = idx & 255;
                int sw = nn ^ ((row & 7) << 3);
                hb0[row * 256 + sw] = (short)h_state[(size_t)(b0 + row) * H_ + nn];
                cb0[row * 256 + sw] = (short)f2bf(c_state[(size_t)(b0 + row) * H_ + nn]);
            }
#pragma unroll
            for (int r = 0; r < 4; r++)
                creg[r] = c_state[(size_t)(b0 + lgrp * 4 + r) * H_ + n];
        }
    }
    const uint2* xg8 = (const uint2*)xgp;
    uint2 xc[4], xn[4];
#pragma unroll
    for (int q = 0; q < 4; q++)
        xc[q] = xg8[((size_t)bblk * 64 + (q * 16 + w)) * 64 + l];
    float dn[4];
#pragma unroll
    for (int r = 0; r < 4; r++)
        dn[r] = dec_in[(size_t)(b0 + lgrp * 4 + r) * S_ + chunk * CHUNK];
    __syncthreads();  // chunk-start full barrier (staging visible)

    // prologue: Wh kk=0 batch into parity 0 of the VGPR stream buffer
    bf16x8 wfb[2][4];
#pragma unroll
    for (int q = 0; q < 4; q++) wfb[0][q] = Whp8[((size_t)(q * 16 + w) * 8 + 0) * 64 + l];

#pragma unroll 1
    for (int t = 0; t < CHUNK; ++t) {
        const int tg = chunk * CHUNK + t;
        const int par = t & 1;
        const short* hb = (const short*)(smem + par * 16384);
        const short* cb = (const short*)(smem + par * 16384 + 8192);
        short* hx = (short*)(smem + (par ^ 1) * 16384);
        short* cx = (short*)(smem + (par ^ 1) * 16384 + 8192);
        // SGPR-side launder: weight loads become formally t-variant (no LICM hoist), but
        // the per-lane offset stays loop-invariant -> addresses are SALU work only.
        const bf16x8* WhpT;
        {
            unsigned long long tz = 0;
            asm volatile("" : "+s"(tz));
            WhpT = (const bf16x8*)((const char*)Whp8 + tz);
        }
        float dcur[4];
#pragma unroll
        for (int r = 0; r < 4; r++) dcur[r] = dn[r];
        f32x4 csacc = {0.f, 0.f, 0.f, 0.f};
        f32x4 gacc[4];
#pragma unroll
        for (int q = 0; q < 4; q++) {
            uint2 v = xc[q];
            gacc[q][0] = bfbits_lo(v.x);
            gacc[q][1] = bfbits_hi(v.x);
            gacc[q][2] = bfbits_lo(v.y);
            gacc[q][3] = bfbits_hi(v.y);
        }
#pragma unroll
        for (int kk = 0; kk < 8; kk++) {
            const int cur = kk & 1, nb = cur ^ 1;
            const int kn = (kk + 1) & 7;  // kk=7 issues next step's kk=0 (same data, L2-hot)
#pragma unroll
            for (int q = 0; q < 4; q++)
                wfb[nb][q] = WhpT[((size_t)(q * 16 + w) * 8 + kn) * 64 + l];
            const int ha = col * 256 + ((kk * 32 + lgrp * 8) ^ ((col & 7) << 3));
            bf16x8 hf = *(const bf16x8*)&hb[ha];
            bf16x8 cf = *(const bf16x8*)&cb[ha];
            csacc = __builtin_amdgcn_mfma_f32_16x16x32_bf16(cf, wd[kk], csacc, 0, 0, 0);
#pragma unroll
            for (int q = 0; q < 4; q++)
                gacc[q] = __builtin_amdgcn_mfma_f32_16x16x32_bf16(hf, wfb[cur][q], gacc[q], 0, 0, 0);
        }
        // prefetch next step's xg + dec (EW below hides latency; port stays busy)
        const int tn = (t + 1 < CHUNK) ? t + 1 : t;
        {
            int rb = tn * 16 + bblk;
#pragma unroll
            for (int q = 0; q < 4; q++)
                xn[q] = xg8[((size_t)rb * 64 + (q * 16 + w)) * 64 + l];
            int tgn = chunk * CHUNK + tn;
#pragma unroll
            for (int r = 0; r < 4; r++)
                dn[r] = dec_in[(size_t)(b0 + lgrp * 4 + r) * S_ + tgn];
        }
        // EW (register-only) + LDS writes to the OTHER parity + global stores
#pragma unroll
        for (int r = 0; r < 4; r++) {
            int row = lgrp * 4 + r;
            float cs = tanhf_(csacc[r] + bdv);
            float cadj = creg[r] - cs + cs * dcur[r];
            float iv = sigmoidf_(gacc[0][r]);
            float fv = sigmoidf_(gacc[1][r]);
            float ov = sigmoidf_(gacc[2][r]);
            float cd = tanhf_(gacc[3][r]);
            float cn = fv * cadj + iv * cd;
            float hn = ov * tanhf_(cn);
            creg[r] = cn;
            int sw = n ^ ((row & 7) << 3);
            unsigned hc;  // packed {bf16(cn) hi, bf16(hn) lo}, RTN in one instruction
            asm("v_cvt_pk_bf16_f32 %0, %1, %2" : "=v"(hc) : "v"(hn), "v"(cn));
            unsigned short hnb = (unsigned short)hc;
            hx[row * 256 + sw] = (short)hnb;
            cx[row * 256 + sw] = (short)(hc >> 16);
            size_t yi = ((size_t)(b0 + row) * S_ + tg) * H_ + n;
            if constexpr (ISL0) {
                ((unsigned short*)yout)[yi] = hnb;
                if (w == 15 && col == 15)
                    dec_out[(size_t)(b0 + row) * S_ + tg] = 1.f / __logf(2.718281828459045f + hn);
            } else {
                ((float*)yout)[yi] = hn;
            }
            if (t == CHUNK - 1) {
                h_state[(size_t)(b0 + row) * H_ + n] = hnb;
                c_state[(size_t)(b0 + row) * H_ + n] = cn;
                if (tail) {  // final chunk: write f32 h/c tail of d_out directly
                    tail[(size_t)(b0 + row) * H_ + n] = hn;
                    tail[65536 + (size_t)(b0 + row) * H_ + n] = cn;
                }
            }
        }
        // SINGLE barrier per step: publish LDS writes (lgkm only — no VMEM drain).
        asm volatile("s_waitcnt lgkmcnt(0)" ::: "memory");
        __builtin_amdgcn_s_barrier();
        __builtin_amdgcn_sched_barrier(0);
#pragma unroll
        for (int q = 0; q < 4; q++) xc[q] = xn[q];
    }
}

__global__ __launch_bounds__(1024, 4) void rec_fused(
    const unsigned short* __restrict__ xgpA, const unsigned short* __restrict__ Whp0,
    const unsigned short* __restrict__ Wdp0, const float* __restrict__ bd0,
    const float* __restrict__ dec0, unsigned short* __restrict__ y0bf,
    float* __restrict__ dec1, unsigned short* __restrict__ hs0, float* __restrict__ cs0,
    const unsigned short* __restrict__ xgpB, const unsigned short* __restrict__ Whp1,
    const unsigned short* __restrict__ Wdp1, const float* __restrict__ bd1,
    float* __restrict__ y1, unsigned short* __restrict__ hs1, float* __restrict__ cs1,
    float* __restrict__ tail0, float* __restrict__ tail1, int c0, int c1) {
    extern __shared__ char smem[];
    int lay = blockIdx.x >> 4, bblk = blockIdx.x & 15;
    if (lay == 0) {
        if (c0 < 0) return;
        rec_run<true>(xgpA, (const bf16x8*)Whp0, (const bf16x8*)Wdp0, bd0, dec0, y0bf, dec1,
                      hs0, cs0, (c0 == NCHUNK - 1) ? tail0 : nullptr, c0, bblk, smem);
    } else {
        if (c1 < 0) return;
        rec_run<false>(xgpB, (const bf16x8*)Whp1, (const bf16x8*)Wdp1, bd1, dec1, y1, nullptr,
                       hs1, cs1, (c1 == NCHUNK - 1) ? tail1 : nullptr, c1, bblk, smem);
    }
}

extern "C" void kernel_launch(void* const* d_in, const int* in_sizes, int n_in, void* d_out,
                              int out_size, void* d_ws, size_t ws_size, hipStream_t stream) {
    (void)in_sizes; (void)n_in; (void)out_size; (void)ws_size;
    const float* x   = (const float*)d_in[0];
    const float* Wx0 = (const float*)d_in[1];
    const float* Wh0 = (const float*)d_in[2];
    const float* b0  = (const float*)d_in[3];
    const float* Wd0 = (const float*)d_in[4];
    const float* bd0 = (const float*)d_in[5];
    const float* Wx1 = (const float*)d_in[6];
    const float* Wh1 = (const float*)d_in[7];
    const float* b1  = (const float*)d_in[8];
    const float* Wd1 = (const float*)d_in[9];
    const float* bd1 = (const float*)d_in[10];

    char* ws = (char*)d_ws;
    size_t off = 0;
    auto take = [&](size_t bytes) { void* p = ws + off; off += (bytes + 255) & ~(size_t)255; return p; };
    unsigned short* wxp0 = (unsigned short*)take(524288);
    unsigned short* whp0 = (unsigned short*)take(524288);
    unsigned short* wdp0 = (unsigned short*)take(131072);
    unsigned short* wxp1 = (unsigned short*)take(524288);
    unsigned short* whp1 = (unsigned short*)take(524288);
    unsigned short* wdp1 = (unsigned short*)take(131072);
    float* dec0 = (float*)take(524288);
    float* dec1 = (float*)take(524288);
    unsigned short* hs0 = (unsigned short*)take(131072);
    float* cs0 = (float*)take(262144);
    unsigned short* hs1 = (unsigned short*)take(131072);
    float* cs1 = (float*)take(262144);
    unsigned short* y0bf = (unsigned short*)take(67108864);
    unsigned short* xgpA = (unsigned short*)take(16777216);
    unsigned short* xgpB = (unsigned short*)take(16777216);

    const size_t smem_rec = 32768;  // h/c parity double buffer
    (void)hipFuncSetAttribute(reinterpret_cast<const void*>(&rec_fused),
                              hipFuncAttributeMaxDynamicSharedMemorySize, (int)smem_rec);
    (void)hipFuncSetAttribute(reinterpret_cast<const void*>(&gemm_dual),
                              hipFuncAttributeMaxDynamicSharedMemorySize, 65536);

    prep_w<<<128, 256, 0, stream>>>(Wx0, wxp0, 64);
    prep_w<<<128, 256, 0, stream>>>(Wh0, whp0, 64);
    prep_w<<<32, 256, 0, stream>>>(Wd0, wdp0, 16);
    prep_w<<<128, 256, 0, stream>>>(Wx1, wxp1, 64);
    prep_w<<<128, 256, 0, stream>>>(Wh1, whp1, 64);
    prep_w<<<32, 256, 0, stream>>>(Wd1, wdp1, 16);
    prep_decay<<<512, 256, 0, stream>>>(x, dec0, B_ * S_);

    float* y1 = (float*)d_out;
    float* tail0 = y1 + (size_t)B_ * S_ * H_;            // [h0|c0] f32
    float* tail1 = tail0 + 2 * 65536;                    // [h1|c1] f32
    for (int s = 0; s <= NCHUNK; ++s) {
        int c0 = (s < NCHUNK) ? s : -1;
        int c1 = (s >= 1) ? s - 1 : -1;
        gemm_dual<<<dim3(64, 8, 2), 256, 65536, stream>>>(x, y0bf, wxp0, b0, wxp1, b1,
                                                          xgpA, xgpB, c0, c1);
        rec_fused<<<32, 1024, smem_rec, stream>>>(xgpA, whp0, wdp0, bd0, dec0, y0bf, dec1,
                                                  hs0, cs0, xgpB, whp1, wdp1, bd1, y1,
                                                  hs1, cs1, tail0, tail1, c0, c1);
    }
}